// Round 1
// baseline (162.609 us; speedup 1.0000x reference)
//
#include <hip/hip_runtime.h>

#define N_TOK   32768
#define NEMBED  1024
#define SCALE   32.0f   // sqrt(1024)

__device__ __forceinline__ int bucket_of(int idx) {
    return (idx < 20000) ? 0 : (idx < 40000) ? 1 : (idx < 200000) ? 2 : 3;
}

// ---------------- classify + compact tokens into per-bucket lists ----------------
__global__ void classify_kernel(const int* __restrict__ x,
                                int* __restrict__ cnt,      // [4]
                                int* __restrict__ lists) {  // [4][N_TOK]
    __shared__ int s_cnt[4], s_base[4];
    int tid = threadIdx.x;
    if (tid < 4) s_cnt[tid] = 0;
    __syncthreads();
    int t = blockIdx.x * blockDim.x + tid;
    int b = 0, p = 0;
    if (t < N_TOK) {
        b = bucket_of(x[t]);
        p = atomicAdd(&s_cnt[b], 1);
    }
    __syncthreads();
    if (tid < 4) s_base[tid] = atomicAdd(&cnt[tid], s_cnt[tid]);
    __syncthreads();
    if (t < N_TOK) lists[b * N_TOK + s_base[b] + p] = t;
}

// ---------------- bucket 0: pure row copy (d == 1024), scale by 32 ----------------
__global__ void embed0_kernel(const int* __restrict__ x,
                              const float* __restrict__ table0,
                              const int* __restrict__ cnt,
                              const int* __restrict__ list0,
                              float* __restrict__ out) {
    int n = cnt[0];
    int tid = threadIdx.x;
    for (int i = blockIdx.x; i < n; i += gridDim.x) {
        int t = list0[i];
        int idx = x[t];
        float4 v = ((const float4*)(table0 + (size_t)idx * NEMBED))[tid];
        v.x *= SCALE; v.y *= SCALE; v.z *= SCALE; v.w *= SCALE;
        ((float4*)(out + (size_t)t * NEMBED))[tid] = v;
    }
}

// ---------------- buckets 1..3: gather TM rows -> E(LDS), E @ proj -> out ----------------
// block = 256 threads; thread tid owns output columns [4*tid, 4*tid+3].
template <int D, int TM>
__global__ __launch_bounds__(256)
void embed_proj_kernel(const int* __restrict__ x,
                       const float* __restrict__ table,   // [rows, D]
                       const float* __restrict__ proj,    // [D, 1024]
                       const int* __restrict__ cnt,       // [4]
                       const int* __restrict__ list_b,    // this bucket's token list
                       float* __restrict__ out,
                       int b, int start) {
    __shared__ float E[TM * D];
    __shared__ int s_tok[TM];
    __shared__ int s_row[TM];

    int n = cnt[b];
    int nchunk = (n + TM - 1) / TM;
    int tid = threadIdx.x;

    for (int chunk = blockIdx.x; chunk < nchunk; chunk += gridDim.x) {
        int base = chunk * TM;
        if (tid < TM) {
            int i = base + tid;
            int tok = (i < n) ? list_b[i] : -1;
            s_tok[tid] = tok;
            s_row[tid] = (tok >= 0) ? (x[tok] - start) : -1;
        }
        __syncthreads();

        // stage embedding rows into LDS (zeros for padding rows)
        for (int i = tid; i < TM * D; i += 256) {
            int tt = i / D, k = i % D;
            int row = s_row[tt];
            E[i] = (row >= 0) ? table[(size_t)row * D + k] : 0.0f;
        }
        __syncthreads();

        float4 acc[TM];
        #pragma unroll
        for (int t = 0; t < TM; t++) acc[t] = make_float4(0.f, 0.f, 0.f, 0.f);

        for (int k0 = 0; k0 < D; k0 += 4) {
            float4 p0 = ((const float4*)(proj + (size_t)(k0 + 0) * NEMBED))[tid];
            float4 p1 = ((const float4*)(proj + (size_t)(k0 + 1) * NEMBED))[tid];
            float4 p2 = ((const float4*)(proj + (size_t)(k0 + 2) * NEMBED))[tid];
            float4 p3 = ((const float4*)(proj + (size_t)(k0 + 3) * NEMBED))[tid];
            #pragma unroll
            for (int t = 0; t < TM; t++) {
                float4 e = *(const float4*)&E[t * D + k0];   // wave-broadcast LDS read
                acc[t].x += e.x * p0.x + e.y * p1.x + e.z * p2.x + e.w * p3.x;
                acc[t].y += e.x * p0.y + e.y * p1.y + e.z * p2.y + e.w * p3.y;
                acc[t].z += e.x * p0.z + e.y * p1.z + e.z * p2.z + e.w * p3.z;
                acc[t].w += e.x * p0.w + e.y * p1.w + e.z * p2.w + e.w * p3.w;
            }
        }

        #pragma unroll
        for (int t = 0; t < TM; t++) {
            int tok = s_tok[t];
            if (tok >= 0) {
                float4 v;
                v.x = acc[t].x * SCALE; v.y = acc[t].y * SCALE;
                v.z = acc[t].z * SCALE; v.w = acc[t].w * SCALE;
                ((float4*)(out + (size_t)tok * NEMBED))[tid] = v;
            }
        }
        __syncthreads();   // protect E/s_tok before next chunk
    }
}

extern "C" void kernel_launch(void* const* d_in, const int* in_sizes, int n_in,
                              void* d_out, int out_size, void* d_ws, size_t ws_size,
                              hipStream_t stream) {
    const int*   x  = (const int*)d_in[0];
    const float* t0 = (const float*)d_in[1];
    const float* t1 = (const float*)d_in[2];
    const float* t2 = (const float*)d_in[3];
    const float* t3 = (const float*)d_in[4];
    const float* p1 = (const float*)d_in[5];
    const float* p2 = (const float*)d_in[6];
    const float* p3 = (const float*)d_in[7];
    float* out = (float*)d_out;

    int* cnt   = (int*)d_ws;          // [4] (+ padding to 64 ints)
    int* lists = cnt + 64;            // [4][N_TOK]

    hipMemsetAsync(d_ws, 0, 64 * sizeof(int), stream);
    classify_kernel<<<N_TOK / 256, 256, 0, stream>>>(x, cnt, lists);

    embed0_kernel<<<1024, 256, 0, stream>>>(x, t0, cnt, lists + 0 * N_TOK, out);
    embed_proj_kernel<256, 16><<<1024, 256, 0, stream>>>(x, t1, p1, cnt, lists + 1 * N_TOK, out, 1, 20000);
    embed_proj_kernel< 64, 16><<<1024, 256, 0, stream>>>(x, t2, p2, cnt, lists + 2 * N_TOK, out, 2, 40000);
    embed_proj_kernel< 16, 16><<<1024, 256, 0, stream>>>(x, t3, p3, cnt, lists + 3 * N_TOK, out, 3, 200000);
}